// Round 8
// baseline (350.881 us; speedup 1.0000x reference)
//
#include <hip/hip_runtime.h>
#include <hip/hip_fp16.h>
#include <math.h>

// ---------------------------------------------------------------------------
// AttnEncoder: 2-layer GAT on two graphs + softmax gating head.
//  - CSR build with fixed-capacity buckets; per-wave histograms in sort.
//  - k_bin_scatter: graph-parallel via blockIdx.y (R7 win, -6us).
//  - k_prepw: W transposed+fp16+padded once into global (+ bucket init).
//  - k_sortgemm1: grid-fused sort || layer-1 GEMM (R4 structure; LDS-staged
//    weights — R5 de-staging regressed via L1 thrash).
//  - GEMM via v_mfma_f32_16x16x32_f16, fp32 acc, fused S/D scalars.
//  - Aggregation: v1 core (16-edge groups, 4 gather loads in flight) —
//    DO NOT TOUCH agg_core (R1/R2/R3/R6 inner restructures all regressed;
//    sits at ~2.8-3.1 TB/s random-256B-row service plateau, 244MB L2-miss).
//    R8: grid-stride wrapper (2048 blocks = 8/CU full residency) with
//    one-iteration software pipelining of the per-node scalar prologue
//    (off/dend/D prefetched before current node's gathers).
//  - R6 lesson: never barrier-couple variable-latency gather waves with
//    fixed-work MFMA waves.
//  - Layer-2 aggregation fused with the prediction head.
// ---------------------------------------------------------------------------

#define LRELU(v) ((v) > 0.f ? (v) : 0.2f * (v))

#define BSHIFT 7
#define BSIZE  128
#define MAXB   512
#define CHUNK  4096
#define EPT    16
#define MAXE   4352
#define CAPI   (MAXE + BSIZE)
#define WTSZ   17408            // 128*136 halves per transposed W

typedef _Float16 half8 __attribute__((ext_vector_type(8)));
typedef float f32x4 __attribute__((ext_vector_type(4)));

// ---- CSR build -------------------------------------------------------------

__global__ __launch_bounds__(256) void k_bin_scatter(
    const int* __restrict__ src_o, const int* __restrict__ dst_o,
    const int* __restrict__ src_s, const int* __restrict__ dst_s,
    int* bcur_o, int* bcur_s, int* ebin_o, int* ebin_s, int E)
{
    __shared__ int cnt[MAXB];
    __shared__ int gb[MAXB];
    int t = threadIdx.x;
    int base = blockIdx.x * CHUNK;
    int g = blockIdx.y;

    const int* srcp = g ? src_s : src_o;
    const int* dstp = g ? dst_s : dst_o;
    int* bcur = g ? bcur_s : bcur_o;
    int* ebin = g ? ebin_s : ebin_o;
    for (int i = t; i < MAXB; i += 256) cnt[i] = 0;
    __syncthreads();
    int pk[EPT], bk[EPT], rk[EPT];
    #pragma unroll
    for (int j = 0; j < EPT; j++) {
        int e = base + j * 256 + t;
        bk[j] = -1; pk[j] = 0; rk[j] = 0;
        if (e < E) {
            int d = dstp[e];
            int s = srcp[e];
            int bb = d >> BSHIFT;
            bk[j] = bb;
            pk[j] = ((d & (BSIZE - 1)) << 16) | s;
            rk[j] = atomicAdd(&cnt[bb], 1);
        }
    }
    __syncthreads();
    for (int i = t; i < MAXB; i += 256) {
        int c = cnt[i];
        gb[i] = c ? atomicAdd(&bcur[i], c) : 0;
    }
    __syncthreads();
    #pragma unroll
    for (int j = 0; j < EPT; j++) {
        if (bk[j] >= 0) {
            int p = gb[bk[j]] + rk[j];
            if (p < (bk[j] + 1) * MAXE) ebin[p] = pk[j];
        }
    }
}

// ---- W prep (+ bucket cursor init) ----------------------------------------

__global__ __launch_bounds__(256) void k_prepw(
    const float* __restrict__ W0, const float* __restrict__ W1,
    const float* __restrict__ W2, const float* __restrict__ W3,
    _Float16* __restrict__ WtG, int* bcur_o, int* bcur_s, int nbuck)
{
    int i = blockIdx.x * 256 + threadIdx.x;
    if (i < nbuck) { bcur_o[i] = i * MAXE; bcur_s[i] = i * MAXE; }
    int w = i >> 14;
    int rem = i & 16383;
    int nn = rem >> 7;
    int k = rem & 127;
    const float* W = (w == 0) ? W0 : (w == 1) ? W1 : (w == 2) ? W2 : W3;
    WtG[w * WTSZ + nn * 136 + k] = (_Float16)W[k * 128 + nn];
}

// ---- shared GEMM helpers ---------------------------------------------------

__device__ __forceinline__ void sd_epilogue(
    const f32x4* acc, const float* a_src, const float* a_dst,
    float* Svec, float* Dvec, int m0, int wave, int lane, int m, int q, int n)
{
    float sp[4] = {0.f, 0.f, 0.f, 0.f};
    float dp[4] = {0.f, 0.f, 0.f, 0.f};
    #pragma unroll
    for (int nt = 0; nt < 8; nt++) {
        float asv = a_src[nt * 16 + m];
        float adv = a_dst[nt * 16 + m];
        #pragma unroll
        for (int r = 0; r < 4; r++) {
            sp[r] = fmaf(acc[nt][r], asv, sp[r]);
            dp[r] = fmaf(acc[nt][r], adv, dp[r]);
        }
    }
    #pragma unroll
    for (int msk = 1; msk < 16; msk <<= 1) {
        #pragma unroll
        for (int r = 0; r < 4; r++) {
            sp[r] += __shfl_xor(sp[r], msk);
            dp[r] += __shfl_xor(dp[r], msk);
        }
    }
    if (m == 0) {
        #pragma unroll
        for (int r = 0; r < 4; r++) {
            int row = m0 + wave * 16 + q * 4 + r;
            if (row < n) { Svec[row] = sp[r]; Dvec[row] = dp[r]; }
        }
    }
}

__device__ __forceinline__ void d_to_lds(
    _Float16* As, const f32x4* acc, int wave, int m, int q)
{
    #pragma unroll
    for (int nt = 0; nt < 8; nt++) {
        #pragma unroll
        for (int r = 0; r < 4; r++) {
            As[(wave * 16 + q * 4 + r) * 136 + nt * 16 + m] = (_Float16)acc[nt][r];
        }
    }
}

__device__ __forceinline__ void lds_to_h(
    const _Float16* As, __half* H, int m0, int tid, int n)
{
    for (int i = tid; i < 1024; i += 256) {
        int r = i >> 4;
        int c8 = (i & 15) << 3;
        int row = m0 + r;
        if (row < n)
            *(uint4*)&H[(size_t)row * 128 + c8] = *(const uint4*)&As[r * 136 + c8];
    }
}

// ---- sort role body (one block per bucket, LDS counting sort) -------------

__device__ __forceinline__ void sort_body(
    char* SMEM, int b,
    const int* __restrict__ ebin, const int* __restrict__ bcur,
    int* __restrict__ off, int* __restrict__ dend,
    unsigned short* __restrict__ idx, int N)
{
    int* pack   = (int*)SMEM;                    // MAXE
    int* sorted = pack + MAXE;                   // MAXE + BSIZE
    int* cnt4   = sorted + MAXE + BSIZE;         // 4*(BSIZE+1)
    int* s2     = cnt4 + 4 * (BSIZE + 1);        // BSIZE+1
    int* noff   = s2 + (BSIZE + 1);              // BSIZE+1

    int t = threadIdx.x;
    int wave = t >> 6;
    int node0 = b << BSHIFT;
    int nloc = min(BSIZE, N - node0);
    int ebeg = b * MAXE;
    int ne = min(bcur[b] - ebeg, MAXE);
    int ib = b * CAPI;

    for (int i = t; i < ne; i += 256) pack[i] = ebin[ebeg + i];
    for (int i = t; i < 4 * (BSIZE + 1); i += 256) cnt4[i] = 0;
    __syncthreads();
    for (int i = t; i < ne; i += 256)
        atomicAdd(&cnt4[wave * (BSIZE + 1) + (pack[i] >> 16)], 1);
    __syncthreads();
    int c0 = 0, c1 = 0, c2 = 0, c3 = 0, selfc = 0;
    if (t < BSIZE + 1) {
        c0 = cnt4[0 * (BSIZE + 1) + t];
        c1 = cnt4[1 * (BSIZE + 1) + t];
        c2 = cnt4[2 * (BSIZE + 1) + t];
        c3 = cnt4[3 * (BSIZE + 1) + t];
        selfc = (t < nloc) ? 1 : 0;
        s2[t] = c0 + c1 + c2 + c3 + selfc;
    }
    __syncthreads();
    for (int d = 1; d <= BSIZE; d <<= 1) {
        int v = (t < BSIZE + 1 && t >= d) ? s2[t - d] : 0;
        __syncthreads();
        if (t < BSIZE + 1) s2[t] += v;
        __syncthreads();
    }
    if (t < BSIZE + 1) noff[t] = s2[t] - (c0 + c1 + c2 + c3 + selfc);
    __syncthreads();
    if (t < nloc) {
        int base0 = noff[t] + 1;                // slot 0 = self loop
        cnt4[0 * (BSIZE + 1) + t] = base0;
        cnt4[1 * (BSIZE + 1) + t] = base0 + c0;
        cnt4[2 * (BSIZE + 1) + t] = base0 + c0 + c1;
        cnt4[3 * (BSIZE + 1) + t] = base0 + c0 + c1 + c2;
        sorted[noff[t]] = node0 + t;
        off[node0 + t]  = ib + noff[t];
        dend[node0 + t] = ib + s2[t];
    }
    __syncthreads();
    for (int i = t; i < ne; i += 256) {
        int p = atomicAdd(&cnt4[wave * (BSIZE + 1) + (pack[i] >> 16)], 1);
        sorted[p] = pack[i] & 0xffff;
    }
    __syncthreads();
    int tot = ne + nloc;
    for (int i = t; i < tot; i += 256) idx[ib + i] = (unsigned short)sorted[i];
}

// ---- gemm1 role body: X staged once, both branch weights (R4) -------------

__device__ __forceinline__ void gemm1_body(
    char* SMEM, int m0,
    const float* __restrict__ X,
    const _Float16* __restrict__ WtO, const _Float16* __restrict__ WtS,
    const float* __restrict__ asO, const float* __restrict__ adO,
    const float* __restrict__ asS, const float* __restrict__ adS,
    __half* __restrict__ HO, __half* __restrict__ HS,
    float* __restrict__ SO, float* __restrict__ DO,
    float* __restrict__ SS, float* __restrict__ DS, int n)
{
    _Float16* As = (_Float16*)SMEM;              // 64*136
    _Float16* Wt = As + 64 * 136;                // 128*136
    int tid = threadIdx.x;

    for (int i = tid; i < WTSZ / 8; i += 256)
        ((uint4*)Wt)[i] = ((const uint4*)WtO)[i];
    for (int i = tid; i < 64 * 32; i += 256) {
        int r = i >> 5;
        int c4 = (i & 31) << 2;
        int row = m0 + r; if (row >= n) row = n - 1;
        float4 v = *(const float4*)&X[(size_t)row * 128 + c4];
        _Float16* p = &As[r * 136 + c4];
        p[0] = (_Float16)v.x; p[1] = (_Float16)v.y;
        p[2] = (_Float16)v.z; p[3] = (_Float16)v.w;
    }
    __syncthreads();

    int wave = tid >> 6;
    int lane = tid & 63;
    int m = lane & 15;
    int q = lane >> 4;
    int arow = wave * 16 + m;

    f32x4 accO[8], accS[8];
    #pragma unroll
    for (int nt = 0; nt < 8; nt++) accO[nt] = (f32x4){0.f, 0.f, 0.f, 0.f};
    #pragma unroll
    for (int k0 = 0; k0 < 128; k0 += 32) {
        half8 a = *(half8*)&As[arow * 136 + k0 + q * 8];
        #pragma unroll
        for (int nt = 0; nt < 8; nt++) {
            half8 b = *(half8*)&Wt[(nt * 16 + m) * 136 + k0 + q * 8];
            accO[nt] = __builtin_amdgcn_mfma_f32_16x16x32_f16(a, b, accO[nt], 0, 0, 0);
        }
    }
    sd_epilogue(accO, asO, adO, SO, DO, m0, wave, lane, m, q, n);
    __syncthreads();
    for (int i = tid; i < WTSZ / 8; i += 256)
        ((uint4*)Wt)[i] = ((const uint4*)WtS)[i];
    __syncthreads();
    #pragma unroll
    for (int nt = 0; nt < 8; nt++) accS[nt] = (f32x4){0.f, 0.f, 0.f, 0.f};
    #pragma unroll
    for (int k0 = 0; k0 < 128; k0 += 32) {
        half8 a = *(half8*)&As[arow * 136 + k0 + q * 8];
        #pragma unroll
        for (int nt = 0; nt < 8; nt++) {
            half8 b = *(half8*)&Wt[(nt * 16 + m) * 136 + k0 + q * 8];
            accS[nt] = __builtin_amdgcn_mfma_f32_16x16x32_f16(a, b, accS[nt], 0, 0, 0);
        }
    }
    sd_epilogue(accS, asS, adS, SS, DS, m0, wave, lane, m, q, n);

    __syncthreads();
    d_to_lds(As, accO, wave, m, q);
    __syncthreads();
    lds_to_h(As, HO, m0, tid, n);
    __syncthreads();
    d_to_lds(As, accS, wave, m, q);
    __syncthreads();
    lds_to_h(As, HS, m0, tid, n);
}

// ---- fused sort || gemm1 (independent work after bin_scatter) -------------

__global__ __launch_bounds__(256) void k_sortgemm1(
    const int* __restrict__ ebin_o, const int* __restrict__ bcur_o,
    int* __restrict__ off_o, int* __restrict__ dend_o, unsigned short* __restrict__ idx_o,
    const int* __restrict__ ebin_s, const int* __restrict__ bcur_s,
    int* __restrict__ off_s, int* __restrict__ dend_s, unsigned short* __restrict__ idx_s,
    const float* __restrict__ X,
    const _Float16* __restrict__ WtO, const _Float16* __restrict__ WtS,
    const float* __restrict__ asO, const float* __restrict__ adO,
    const float* __restrict__ asS, const float* __restrict__ adS,
    __half* __restrict__ HO, __half* __restrict__ HS,
    float* __restrict__ SO, float* __restrict__ DO,
    float* __restrict__ SS, float* __restrict__ DS,
    int N, int nbuck)
{
    __shared__ __align__(16) char SMEM[52224];   // max(sort 38424, gemm 52224)
    int bid = blockIdx.x;
    if (bid < 2 * nbuck) {
        if (bid < nbuck)
            sort_body(SMEM, bid, ebin_o, bcur_o, off_o, dend_o, idx_o, N);
        else
            sort_body(SMEM, bid - nbuck, ebin_s, bcur_s, off_s, dend_s, idx_s, N);
    } else {
        gemm1_body(SMEM, (bid - 2 * nbuck) * 64, X, WtO, WtS,
                   asO, adO, asS, adS, HO, HS, SO, DO, SS, DS, N);
    }
}

// ---- layer-2 GEMM (branch pair via blockIdx.y, fp16 input) ----------------

__global__ __launch_bounds__(256) void k_gemm2(
    const __half* __restrict__ X0, const __half* __restrict__ X1,
    const _Float16* __restrict__ WtA, const _Float16* __restrict__ WtB,
    const float* __restrict__ as0, const float* __restrict__ ad0,
    const float* __restrict__ as1, const float* __restrict__ ad1,
    __half* __restrict__ H0, __half* __restrict__ H1,
    float* __restrict__ S0, float* __restrict__ D0,
    float* __restrict__ S1, float* __restrict__ D1,
    int n)
{
    int br = blockIdx.y;
    const __half* X = br ? X1 : X0;
    const _Float16* WtGp = br ? WtB : WtA;
    const float* a_src = br ? as1 : as0;
    const float* a_dst = br ? ad1 : ad0;
    __half* H = br ? H1 : H0;
    float* Svec = br ? S1 : S0;
    float* Dvec = br ? D1 : D0;

    __shared__ _Float16 As[64 * 136];
    __shared__ _Float16 Wt[128 * 136];
    int tid = threadIdx.x;
    int m0 = blockIdx.x * 64;

    for (int i = tid; i < WTSZ / 8; i += 256)
        ((uint4*)Wt)[i] = ((const uint4*)WtGp)[i];
    for (int i = tid; i < 64 * 16; i += 256) {
        int r = i >> 4;
        int c8 = (i & 15) << 3;
        int row = m0 + r; if (row >= n) row = n - 1;
        *(uint4*)&As[r * 136 + c8] = *(const uint4*)&X[(size_t)row * 128 + c8];
    }
    __syncthreads();

    int wave = tid >> 6;
    int lane = tid & 63;
    int m = lane & 15;
    int q = lane >> 4;
    int arow = wave * 16 + m;

    f32x4 acc[8];
    #pragma unroll
    for (int nt = 0; nt < 8; nt++) acc[nt] = (f32x4){0.f, 0.f, 0.f, 0.f};
    #pragma unroll
    for (int k0 = 0; k0 < 128; k0 += 32) {
        half8 a = *(half8*)&As[arow * 136 + k0 + q * 8];
        #pragma unroll
        for (int nt = 0; nt < 8; nt++) {
            half8 b = *(half8*)&Wt[(nt * 16 + m) * 136 + k0 + q * 8];
            acc[nt] = __builtin_amdgcn_mfma_f32_16x16x32_f16(a, b, acc[nt], 0, 0, 0);
        }
    }
    sd_epilogue(acc, a_src, a_dst, Svec, Dvec, m0, wave, lane, m, q, n);
    __syncthreads();
    d_to_lds(As, acc, wave, m, q);
    __syncthreads();
    lds_to_h(As, H, m0, tid, n);
}

// ---- aggregation core: one wave, one node (v1 — DO NOT TOUCH) -------------
// 16-edge groups, 4 gather loads in flight; w (float) and s (int) shuffled
// separately - short dependency chains. At the ~2.8-3.1 TB/s random-access
// service plateau (four structural variants all land here).

__device__ __forceinline__ void agg_core(
    const __half* __restrict__ H, const float* __restrict__ Svec, float dn,
    const unsigned short* __restrict__ idx, int beg, int end,
    int lane, int q, int subl, float* acc, float& denom)
{
    #pragma unroll
    for (int j = 0; j < 8; j++) acc[j] = 0.f;
    denom = 0.f;
    for (int base = beg; base < end; base += 64) {
        int cnt = min(64, end - base);
        float w = 0.f;
        int s = 0;
        if (lane < cnt) {
            s = idx[base + lane];
            w = __expf(LRELU(Svec[s] + dn));
        }
        denom += w;
        int cnt16 = (cnt + 15) & ~15;   // pad lanes carry w=0, s=0
        for (int kk = 0; kk < cnt16; kk += 16) {
            int k0 = kk + q;
            float w0 = __shfl(w, k0);
            float w1 = __shfl(w, k0 + 4);
            float w2 = __shfl(w, k0 + 8);
            float w3 = __shfl(w, k0 + 12);
            int s0 = __shfl(s, k0);
            int s1 = __shfl(s, k0 + 4);
            int s2 = __shfl(s, k0 + 8);
            int s3 = __shfl(s, k0 + 12);
            uint4 u0 = ((const uint4*)(H + (size_t)s0 * 128))[subl];
            uint4 u1 = ((const uint4*)(H + (size_t)s1 * 128))[subl];
            uint4 u2 = ((const uint4*)(H + (size_t)s2 * 128))[subl];
            uint4 u3 = ((const uint4*)(H + (size_t)s3 * 128))[subl];
            const _Float16* p;
            p = (const _Float16*)&u0;
            #pragma unroll
            for (int j = 0; j < 8; j++) acc[j] = fmaf((float)p[j], w0, acc[j]);
            p = (const _Float16*)&u1;
            #pragma unroll
            for (int j = 0; j < 8; j++) acc[j] = fmaf((float)p[j], w1, acc[j]);
            p = (const _Float16*)&u2;
            #pragma unroll
            for (int j = 0; j < 8; j++) acc[j] = fmaf((float)p[j], w2, acc[j]);
            p = (const _Float16*)&u3;
            #pragma unroll
            for (int j = 0; j < 8; j++) acc[j] = fmaf((float)p[j], w3, acc[j]);
        }
    }
    #pragma unroll
    for (int j = 0; j < 8; j++) {
        acc[j] += __shfl_xor(acc[j], 16);
        acc[j] += __shfl_xor(acc[j], 32);
    }
    #pragma unroll
    for (int o = 32; o; o >>= 1) denom += __shfl_xor(denom, o);
}

// ---- layer-1 aggregation (branch pair), fp16 out + relu -------------------
// R8: grid-stride over nodes (2048 blocks, full residency) with next-node
// off/dend/D prefetched before the current node's gather loop.

__global__ __launch_bounds__(256) void k_agg1(
    const __half* __restrict__ H0, const __half* __restrict__ H1,
    const float* __restrict__ S0, const float* __restrict__ D0,
    const float* __restrict__ S1, const float* __restrict__ D1,
    const int* __restrict__ off0, const int* __restrict__ dend0,
    const unsigned short* __restrict__ idx0,
    const int* __restrict__ off1, const int* __restrict__ dend1,
    const unsigned short* __restrict__ idx1,
    const float* __restrict__ b0, const float* __restrict__ b1,
    __half* __restrict__ out0, __half* __restrict__ out1,
    int n)
{
    int br = blockIdx.y;
    const __half* H = br ? H1 : H0;
    const float* Svec = br ? S1 : S0;
    const float* Dvec = br ? D1 : D0;
    const int* off  = br ? off1  : off0;
    const int* dend = br ? dend1 : dend0;
    const unsigned short* idx = br ? idx1 : idx0;
    const float* bias = br ? b1 : b0;
    __half* out = br ? out1 : out0;

    int wave = threadIdx.x >> 6;
    int lane = threadIdx.x & 63;
    int q = lane >> 4;
    int subl = lane & 15;
    int stride = gridDim.x * 4;
    int node = blockIdx.x * 4 + wave;
    if (node >= n) return;

    int nOff = off[node];
    int nDend = dend[node];
    float nD = Dvec[node];

    while (node < n) {
        int cOff = nOff, cDend = nDend;
        float cD = nD;
        int nn = node + stride;
        if (nn < n) {                       // prefetch next node's prologue
            nOff = off[nn];
            nDend = dend[nn];
            nD = Dvec[nn];
        }
        float acc[8], denom;
        agg_core(H, Svec, cD, idx, cOff, cDend, lane, q, subl, acc, denom);
        if (q == 0) {
            float inv = 1.f / (denom + 1e-16f);
            int cb = subl << 3;
            half8 hv;
            #pragma unroll
            for (int j = 0; j < 8; j++) {
                float v = fmaxf(acc[j] * inv + bias[cb + j], 0.f);
                hv[j] = (_Float16)v;
            }
            *(half8*)&out[(size_t)node * 128 + cb] = hv;
        }
        node = nn;
    }
}

// ---- layer-2 aggregation + prediction head (both branches per wave) -------
// R8: grid-stride + prologue prefetch, same pattern as k_agg1.

__global__ __launch_bounds__(256) void k_agg_pred(
    const __half* __restrict__ H0, const __half* __restrict__ H1,
    const float* __restrict__ S0, const float* __restrict__ D0,
    const float* __restrict__ S1, const float* __restrict__ D1,
    const int* __restrict__ off0, const int* __restrict__ dend0,
    const unsigned short* __restrict__ idx0,
    const int* __restrict__ off1, const int* __restrict__ dend1,
    const unsigned short* __restrict__ idx1,
    const float* __restrict__ b0, const float* __restrict__ b1,
    const float* __restrict__ deg,
    const float* __restrict__ Wp, const float* __restrict__ bp,
    float* __restrict__ out, int n)
{
    int wave = threadIdx.x >> 6;
    int lane = threadIdx.x & 63;
    int q = lane >> 4;
    int subl = lane & 15;
    int cb = subl << 3;
    int stride = gridDim.x * 4;
    int node = blockIdx.x * 4 + wave;
    if (node >= n) return;

    int nOff0 = off0[node], nDend0 = dend0[node];
    int nOff1 = off1[node], nDend1 = dend1[node];
    float nD0 = D0[node], nD1 = D1[node];

    while (node < n) {
        int cOff0 = nOff0, cDend0 = nDend0;
        int cOff1 = nOff1, cDend1 = nDend1;
        float cD0 = nD0, cD1 = nD1;
        int nn = node + stride;
        if (nn < n) {                       // prefetch next node's prologue
            nOff0 = off0[nn]; nDend0 = dend0[nn]; nD0 = D0[nn];
            nOff1 = off1[nn]; nDend1 = dend1[nn]; nD1 = D1[nn];
        }

        float acc[8], denom;
        float vo[8], vs[8];

        agg_core(H0, S0, cD0, idx0, cOff0, cDend0,
                 lane, q, subl, acc, denom);
        {
            float inv = 1.f / (denom + 1e-16f);
            #pragma unroll
            for (int j = 0; j < 8; j++) vo[j] = acc[j] * inv + b0[cb + j];
        }
        agg_core(H1, S1, cD1, idx1, cOff1, cDend1,
                 lane, q, subl, acc, denom);
        {
            float inv = 1.f / (denom + 1e-16f);
            #pragma unroll
            for (int j = 0; j < 8; j++) vs[j] = acc[j] * inv + b1[cb + j];
        }

        if (q == 0) {
            float z0 = 0.f, z1 = 0.f;
            #pragma unroll
            for (int j = 0; j < 8; j++) {
                int c = cb + j;
                z0 = fmaf(vo[j], Wp[c * 2],     z0);
                z1 = fmaf(vo[j], Wp[c * 2 + 1], z1);
                z0 = fmaf(vs[j], Wp[(128 + c) * 2],     z0);
                z1 = fmaf(vs[j], Wp[(128 + c) * 2 + 1], z1);
            }
            float2 dv = *(const float2*)&deg[(size_t)node * 32 + 2 * subl];
            z0 = fmaf(dv.x, Wp[(256 + 2 * subl) * 2],     z0);
            z1 = fmaf(dv.x, Wp[(256 + 2 * subl) * 2 + 1], z1);
            z0 = fmaf(dv.y, Wp[(257 + 2 * subl) * 2],     z0);
            z1 = fmaf(dv.y, Wp[(257 + 2 * subl) * 2 + 1], z1);
            #pragma unroll
            for (int msk = 1; msk < 16; msk <<= 1) {
                z0 += __shfl_xor(z0, msk);
                z1 += __shfl_xor(z1, msk);
            }
            z0 += bp[0];
            z1 += bp[1];
            float mz = fmaxf(z0, z1);
            float e0 = __expf(z0 - mz);
            float e1 = __expf(z1 - mz);
            float a0 = e0 / (e0 + e1);
            float a1 = 1.f - a0;
            float4 r0, r1;
            r0.x = a0 * vo[0] + a1 * vs[0];
            r0.y = a0 * vo[1] + a1 * vs[1];
            r0.z = a0 * vo[2] + a1 * vs[2];
            r0.w = a0 * vo[3] + a1 * vs[3];
            r1.x = a0 * vo[4] + a1 * vs[4];
            r1.y = a0 * vo[5] + a1 * vs[5];
            r1.z = a0 * vo[6] + a1 * vs[6];
            r1.w = a0 * vo[7] + a1 * vs[7];
            *(float4*)&out[(size_t)node * 128 + cb] = r0;
            *(float4*)&out[(size_t)node * 128 + cb + 4] = r1;
        }
        node = nn;
    }
}

// ---- launch ----------------------------------------------------------------

extern "C" void kernel_launch(void* const* d_in, const int* in_sizes, int n_in,
                              void* d_out, int out_size, void* d_ws, size_t ws_size,
                              hipStream_t stream) {
    const float* x_o    = (const float*)d_in[0];
    const float* degree = (const float*)d_in[1];
    const int*   ei_o   = (const int*)d_in[2];
    const int*   ei_s   = (const int*)d_in[3];
    const float* W_o1 = (const float*)d_in[4];
    const float* asr_o1 = (const float*)d_in[5];
    const float* ads_o1 = (const float*)d_in[6];
    const float* b_o1 = (const float*)d_in[7];
    const float* W_o2 = (const float*)d_in[8];
    const float* asr_o2 = (const float*)d_in[9];
    const float* ads_o2 = (const float*)d_in[10];
    const float* b_o2 = (const float*)d_in[11];
    const float* W_s1 = (const float*)d_in[12];
    const float* asr_s1 = (const float*)d_in[13];
    const float* ads_s1 = (const float*)d_in[14];
    const float* b_s1 = (const float*)d_in[15];
    const float* W_s2 = (const float*)d_in[16];
    const float* asr_s2 = (const float*)d_in[17];
    const float* ads_s2 = (const float*)d_in[18];
    const float* b_s2 = (const float*)d_in[19];
    const float* W_pred = (const float*)d_in[20];
    const float* b_pred = (const float*)d_in[21];
    float* out = (float*)d_out;

    const int N = in_sizes[0] / 128;
    const int E = in_sizes[2] / 2;
    const int NBUCK = (N + BSIZE - 1) >> BSHIFT;

    char* ws = (char*)d_ws;
    size_t o = 0;
    auto alloc = [&](size_t bytes) -> char* {
        char* p = ws + o;
        o += (bytes + 255) & ~(size_t)255;
        return p;
    };
    int* bcur_o = (int*)alloc((size_t)NBUCK * 4);
    int* bcur_s = (int*)alloc((size_t)NBUCK * 4);
    int* off_o  = (int*)alloc((size_t)N * 4);
    int* dend_o = (int*)alloc((size_t)N * 4);
    int* off_s  = (int*)alloc((size_t)N * 4);
    int* dend_s = (int*)alloc((size_t)N * 4);
    unsigned short* idx_o = (unsigned short*)alloc((size_t)NBUCK * CAPI * 2);
    unsigned short* idx_s = (unsigned short*)alloc((size_t)NBUCK * CAPI * 2);
    _Float16* WtG = (_Float16*)alloc((size_t)4 * WTSZ * 2);
    float* Sv_o = (float*)alloc((size_t)N * 4);
    float* Dv_o = (float*)alloc((size_t)N * 4);
    float* Sv_s = (float*)alloc((size_t)N * 4);
    float* Dv_s = (float*)alloc((size_t)N * 4);
    __half* h_o   = (__half*)alloc((size_t)N * 128 * 2);
    __half* h_s   = (__half*)alloc((size_t)N * 128 * 2);
    __half* x1h_o = (__half*)alloc((size_t)N * 128 * 2);
    __half* x1h_s = (__half*)alloc((size_t)N * 128 * 2);
    (void)ws_size;

    // ebin regions overlay x1h (x1h first written by k_agg1, strictly after
    // the fused sort||gemm1 kernel; NBUCK*MAXE*4 = 6.8 MB <= N*128*2)
    int* ebin_o = (int*)x1h_o;
    int* ebin_s = (int*)x1h_s;

    dim3 blk(256);
    int gBin  = (E + CHUNK - 1) / CHUNK;
    int gGemm = (N + 63) / 64;
    int gNode = (N + 3) / 4;
    int gAgg  = gNode < 2048 ? gNode : 2048;   // 8 blocks/CU full residency

    k_prepw<<<256, blk, 0, stream>>>(W_o1, W_o2, W_s1, W_s2, WtG,
                                     bcur_o, bcur_s, NBUCK);
    dim3 gB(gBin, 2);
    k_bin_scatter<<<gB, blk, 0, stream>>>(ei_o, ei_o + E, ei_s, ei_s + E,
                                          bcur_o, bcur_s, ebin_o, ebin_s, E);
    // fused: CSR sort (independent) || layer-1 GEMM
    k_sortgemm1<<<2 * NBUCK + gGemm, blk, 0, stream>>>(
        ebin_o, bcur_o, off_o, dend_o, idx_o,
        ebin_s, bcur_s, off_s, dend_s, idx_s,
        x_o, WtG, WtG + 2 * WTSZ,
        asr_o1, ads_o1, asr_s1, ads_s1,
        h_o, h_s, Sv_o, Dv_o, Sv_s, Dv_s, N, NBUCK);
    dim3 gA(gAgg, 2);
    k_agg1<<<gA, blk, 0, stream>>>(
        h_o, h_s, Sv_o, Dv_o, Sv_s, Dv_s,
        off_o, dend_o, idx_o, off_s, dend_s, idx_s,
        b_o1, b_s1, x1h_o, x1h_s, N);
    // layer 2 (both branches) + fused prediction head
    dim3 gG(gGemm, 2);
    k_gemm2<<<gG, blk, 0, stream>>>(
        x1h_o, x1h_s, WtG + WTSZ, WtG + 3 * WTSZ,
        asr_o2, ads_o2, asr_s2, ads_s2,
        h_o, h_s, Sv_o, Dv_o, Sv_s, Dv_s, N);
    k_agg_pred<<<gAgg, blk, 0, stream>>>(
        h_o, h_s, Sv_o, Dv_o, Sv_s, Dv_s,
        off_o, dend_o, idx_o, off_s, dend_s, idx_s,
        b_o2, b_s2, degree, W_pred, b_pred, out, N);
}

// Round 9
// 344.731 us; speedup vs baseline: 1.0178x; 1.0178x over previous
//
#include <hip/hip_runtime.h>
#include <hip/hip_fp16.h>
#include <math.h>

// ---------------------------------------------------------------------------
// AttnEncoder: 2-layer GAT on two graphs + softmax gating head.
//  - CSR build with fixed-capacity buckets; per-wave histograms in sort.
//  - k_bin_scatter: graph-parallel via blockIdx.y (R7 win, -6us).
//  - k_prepw: W transposed+fp16+padded once into global (+ bucket init).
//  - k_sortgemm1: grid-fused sort || layer-1 GEMM (R4 structure; LDS-staged
//    weights — R5 de-staging regressed via L1 thrash).
//  - GEMM via v_mfma_f32_16x16x32_f16, fp32 acc, fused S/D scalars.
//  - Aggregation: v1 core (16-edge groups, 4 gather loads in flight) at
//    one wave/node, 12500 blocks — DO NOT TOUCH. Probed on five axes:
//    R1 lane-mapping, R2 chain-width, R3 dual-chain, R6 gemm-fusion,
//    R8 grid-stride+prefetch (VGPR 48->64 cost 4% occupancy -> -4us).
//    v1 dominates: 244MB L2-miss random 256B rows at ~3.1 TB/s service
//    rate, needs max occupancy (VGPR<=48) to sustain.
//  - R6 lesson: never barrier-couple variable-latency gather waves with
//    fixed-work MFMA waves.
//  - Layer-2 aggregation fused with the prediction head.
// ---------------------------------------------------------------------------

#define LRELU(v) ((v) > 0.f ? (v) : 0.2f * (v))

#define BSHIFT 7
#define BSIZE  128
#define MAXB   512
#define CHUNK  4096
#define EPT    16
#define MAXE   4352
#define CAPI   (MAXE + BSIZE)
#define WTSZ   17408            // 128*136 halves per transposed W

typedef _Float16 half8 __attribute__((ext_vector_type(8)));
typedef float f32x4 __attribute__((ext_vector_type(4)));

// ---- CSR build -------------------------------------------------------------

__global__ __launch_bounds__(256) void k_bin_scatter(
    const int* __restrict__ src_o, const int* __restrict__ dst_o,
    const int* __restrict__ src_s, const int* __restrict__ dst_s,
    int* bcur_o, int* bcur_s, int* ebin_o, int* ebin_s, int E)
{
    __shared__ int cnt[MAXB];
    __shared__ int gb[MAXB];
    int t = threadIdx.x;
    int base = blockIdx.x * CHUNK;
    int g = blockIdx.y;

    const int* srcp = g ? src_s : src_o;
    const int* dstp = g ? dst_s : dst_o;
    int* bcur = g ? bcur_s : bcur_o;
    int* ebin = g ? ebin_s : ebin_o;
    for (int i = t; i < MAXB; i += 256) cnt[i] = 0;
    __syncthreads();
    int pk[EPT], bk[EPT], rk[EPT];
    #pragma unroll
    for (int j = 0; j < EPT; j++) {
        int e = base + j * 256 + t;
        bk[j] = -1; pk[j] = 0; rk[j] = 0;
        if (e < E) {
            int d = dstp[e];
            int s = srcp[e];
            int bb = d >> BSHIFT;
            bk[j] = bb;
            pk[j] = ((d & (BSIZE - 1)) << 16) | s;
            rk[j] = atomicAdd(&cnt[bb], 1);
        }
    }
    __syncthreads();
    for (int i = t; i < MAXB; i += 256) {
        int c = cnt[i];
        gb[i] = c ? atomicAdd(&bcur[i], c) : 0;
    }
    __syncthreads();
    #pragma unroll
    for (int j = 0; j < EPT; j++) {
        if (bk[j] >= 0) {
            int p = gb[bk[j]] + rk[j];
            if (p < (bk[j] + 1) * MAXE) ebin[p] = pk[j];
        }
    }
}

// ---- W prep (+ bucket cursor init) ----------------------------------------

__global__ __launch_bounds__(256) void k_prepw(
    const float* __restrict__ W0, const float* __restrict__ W1,
    const float* __restrict__ W2, const float* __restrict__ W3,
    _Float16* __restrict__ WtG, int* bcur_o, int* bcur_s, int nbuck)
{
    int i = blockIdx.x * 256 + threadIdx.x;
    if (i < nbuck) { bcur_o[i] = i * MAXE; bcur_s[i] = i * MAXE; }
    int w = i >> 14;
    int rem = i & 16383;
    int nn = rem >> 7;
    int k = rem & 127;
    const float* W = (w == 0) ? W0 : (w == 1) ? W1 : (w == 2) ? W2 : W3;
    WtG[w * WTSZ + nn * 136 + k] = (_Float16)W[k * 128 + nn];
}

// ---- shared GEMM helpers ---------------------------------------------------

__device__ __forceinline__ void sd_epilogue(
    const f32x4* acc, const float* a_src, const float* a_dst,
    float* Svec, float* Dvec, int m0, int wave, int lane, int m, int q, int n)
{
    float sp[4] = {0.f, 0.f, 0.f, 0.f};
    float dp[4] = {0.f, 0.f, 0.f, 0.f};
    #pragma unroll
    for (int nt = 0; nt < 8; nt++) {
        float asv = a_src[nt * 16 + m];
        float adv = a_dst[nt * 16 + m];
        #pragma unroll
        for (int r = 0; r < 4; r++) {
            sp[r] = fmaf(acc[nt][r], asv, sp[r]);
            dp[r] = fmaf(acc[nt][r], adv, dp[r]);
        }
    }
    #pragma unroll
    for (int msk = 1; msk < 16; msk <<= 1) {
        #pragma unroll
        for (int r = 0; r < 4; r++) {
            sp[r] += __shfl_xor(sp[r], msk);
            dp[r] += __shfl_xor(dp[r], msk);
        }
    }
    if (m == 0) {
        #pragma unroll
        for (int r = 0; r < 4; r++) {
            int row = m0 + wave * 16 + q * 4 + r;
            if (row < n) { Svec[row] = sp[r]; Dvec[row] = dp[r]; }
        }
    }
}

__device__ __forceinline__ void d_to_lds(
    _Float16* As, const f32x4* acc, int wave, int m, int q)
{
    #pragma unroll
    for (int nt = 0; nt < 8; nt++) {
        #pragma unroll
        for (int r = 0; r < 4; r++) {
            As[(wave * 16 + q * 4 + r) * 136 + nt * 16 + m] = (_Float16)acc[nt][r];
        }
    }
}

__device__ __forceinline__ void lds_to_h(
    const _Float16* As, __half* H, int m0, int tid, int n)
{
    for (int i = tid; i < 1024; i += 256) {
        int r = i >> 4;
        int c8 = (i & 15) << 3;
        int row = m0 + r;
        if (row < n)
            *(uint4*)&H[(size_t)row * 128 + c8] = *(const uint4*)&As[r * 136 + c8];
    }
}

// ---- sort role body (one block per bucket, LDS counting sort) -------------

__device__ __forceinline__ void sort_body(
    char* SMEM, int b,
    const int* __restrict__ ebin, const int* __restrict__ bcur,
    int* __restrict__ off, int* __restrict__ dend,
    unsigned short* __restrict__ idx, int N)
{
    int* pack   = (int*)SMEM;                    // MAXE
    int* sorted = pack + MAXE;                   // MAXE + BSIZE
    int* cnt4   = sorted + MAXE + BSIZE;         // 4*(BSIZE+1)
    int* s2     = cnt4 + 4 * (BSIZE + 1);        // BSIZE+1
    int* noff   = s2 + (BSIZE + 1);              // BSIZE+1

    int t = threadIdx.x;
    int wave = t >> 6;
    int node0 = b << BSHIFT;
    int nloc = min(BSIZE, N - node0);
    int ebeg = b * MAXE;
    int ne = min(bcur[b] - ebeg, MAXE);
    int ib = b * CAPI;

    for (int i = t; i < ne; i += 256) pack[i] = ebin[ebeg + i];
    for (int i = t; i < 4 * (BSIZE + 1); i += 256) cnt4[i] = 0;
    __syncthreads();
    for (int i = t; i < ne; i += 256)
        atomicAdd(&cnt4[wave * (BSIZE + 1) + (pack[i] >> 16)], 1);
    __syncthreads();
    int c0 = 0, c1 = 0, c2 = 0, c3 = 0, selfc = 0;
    if (t < BSIZE + 1) {
        c0 = cnt4[0 * (BSIZE + 1) + t];
        c1 = cnt4[1 * (BSIZE + 1) + t];
        c2 = cnt4[2 * (BSIZE + 1) + t];
        c3 = cnt4[3 * (BSIZE + 1) + t];
        selfc = (t < nloc) ? 1 : 0;
        s2[t] = c0 + c1 + c2 + c3 + selfc;
    }
    __syncthreads();
    for (int d = 1; d <= BSIZE; d <<= 1) {
        int v = (t < BSIZE + 1 && t >= d) ? s2[t - d] : 0;
        __syncthreads();
        if (t < BSIZE + 1) s2[t] += v;
        __syncthreads();
    }
    if (t < BSIZE + 1) noff[t] = s2[t] - (c0 + c1 + c2 + c3 + selfc);
    __syncthreads();
    if (t < nloc) {
        int base0 = noff[t] + 1;                // slot 0 = self loop
        cnt4[0 * (BSIZE + 1) + t] = base0;
        cnt4[1 * (BSIZE + 1) + t] = base0 + c0;
        cnt4[2 * (BSIZE + 1) + t] = base0 + c0 + c1;
        cnt4[3 * (BSIZE + 1) + t] = base0 + c0 + c1 + c2;
        sorted[noff[t]] = node0 + t;
        off[node0 + t]  = ib + noff[t];
        dend[node0 + t] = ib + s2[t];
    }
    __syncthreads();
    for (int i = t; i < ne; i += 256) {
        int p = atomicAdd(&cnt4[wave * (BSIZE + 1) + (pack[i] >> 16)], 1);
        sorted[p] = pack[i] & 0xffff;
    }
    __syncthreads();
    int tot = ne + nloc;
    for (int i = t; i < tot; i += 256) idx[ib + i] = (unsigned short)sorted[i];
}

// ---- gemm1 role body: X staged once, both branch weights (R4) -------------

__device__ __forceinline__ void gemm1_body(
    char* SMEM, int m0,
    const float* __restrict__ X,
    const _Float16* __restrict__ WtO, const _Float16* __restrict__ WtS,
    const float* __restrict__ asO, const float* __restrict__ adO,
    const float* __restrict__ asS, const float* __restrict__ adS,
    __half* __restrict__ HO, __half* __restrict__ HS,
    float* __restrict__ SO, float* __restrict__ DO,
    float* __restrict__ SS, float* __restrict__ DS, int n)
{
    _Float16* As = (_Float16*)SMEM;              // 64*136
    _Float16* Wt = As + 64 * 136;                // 128*136
    int tid = threadIdx.x;

    for (int i = tid; i < WTSZ / 8; i += 256)
        ((uint4*)Wt)[i] = ((const uint4*)WtO)[i];
    for (int i = tid; i < 64 * 32; i += 256) {
        int r = i >> 5;
        int c4 = (i & 31) << 2;
        int row = m0 + r; if (row >= n) row = n - 1;
        float4 v = *(const float4*)&X[(size_t)row * 128 + c4];
        _Float16* p = &As[r * 136 + c4];
        p[0] = (_Float16)v.x; p[1] = (_Float16)v.y;
        p[2] = (_Float16)v.z; p[3] = (_Float16)v.w;
    }
    __syncthreads();

    int wave = tid >> 6;
    int lane = tid & 63;
    int m = lane & 15;
    int q = lane >> 4;
    int arow = wave * 16 + m;

    f32x4 accO[8], accS[8];
    #pragma unroll
    for (int nt = 0; nt < 8; nt++) accO[nt] = (f32x4){0.f, 0.f, 0.f, 0.f};
    #pragma unroll
    for (int k0 = 0; k0 < 128; k0 += 32) {
        half8 a = *(half8*)&As[arow * 136 + k0 + q * 8];
        #pragma unroll
        for (int nt = 0; nt < 8; nt++) {
            half8 b = *(half8*)&Wt[(nt * 16 + m) * 136 + k0 + q * 8];
            accO[nt] = __builtin_amdgcn_mfma_f32_16x16x32_f16(a, b, accO[nt], 0, 0, 0);
        }
    }
    sd_epilogue(accO, asO, adO, SO, DO, m0, wave, lane, m, q, n);
    __syncthreads();
    for (int i = tid; i < WTSZ / 8; i += 256)
        ((uint4*)Wt)[i] = ((const uint4*)WtS)[i];
    __syncthreads();
    #pragma unroll
    for (int nt = 0; nt < 8; nt++) accS[nt] = (f32x4){0.f, 0.f, 0.f, 0.f};
    #pragma unroll
    for (int k0 = 0; k0 < 128; k0 += 32) {
        half8 a = *(half8*)&As[arow * 136 + k0 + q * 8];
        #pragma unroll
        for (int nt = 0; nt < 8; nt++) {
            half8 b = *(half8*)&Wt[(nt * 16 + m) * 136 + k0 + q * 8];
            accS[nt] = __builtin_amdgcn_mfma_f32_16x16x32_f16(a, b, accS[nt], 0, 0, 0);
        }
    }
    sd_epilogue(accS, asS, adS, SS, DS, m0, wave, lane, m, q, n);

    __syncthreads();
    d_to_lds(As, accO, wave, m, q);
    __syncthreads();
    lds_to_h(As, HO, m0, tid, n);
    __syncthreads();
    d_to_lds(As, accS, wave, m, q);
    __syncthreads();
    lds_to_h(As, HS, m0, tid, n);
}

// ---- fused sort || gemm1 (independent work after bin_scatter) -------------

__global__ __launch_bounds__(256) void k_sortgemm1(
    const int* __restrict__ ebin_o, const int* __restrict__ bcur_o,
    int* __restrict__ off_o, int* __restrict__ dend_o, unsigned short* __restrict__ idx_o,
    const int* __restrict__ ebin_s, const int* __restrict__ bcur_s,
    int* __restrict__ off_s, int* __restrict__ dend_s, unsigned short* __restrict__ idx_s,
    const float* __restrict__ X,
    const _Float16* __restrict__ WtO, const _Float16* __restrict__ WtS,
    const float* __restrict__ asO, const float* __restrict__ adO,
    const float* __restrict__ asS, const float* __restrict__ adS,
    __half* __restrict__ HO, __half* __restrict__ HS,
    float* __restrict__ SO, float* __restrict__ DO,
    float* __restrict__ SS, float* __restrict__ DS,
    int N, int nbuck)
{
    __shared__ __align__(16) char SMEM[52224];   // max(sort 38424, gemm 52224)
    int bid = blockIdx.x;
    if (bid < 2 * nbuck) {
        if (bid < nbuck)
            sort_body(SMEM, bid, ebin_o, bcur_o, off_o, dend_o, idx_o, N);
        else
            sort_body(SMEM, bid - nbuck, ebin_s, bcur_s, off_s, dend_s, idx_s, N);
    } else {
        gemm1_body(SMEM, (bid - 2 * nbuck) * 64, X, WtO, WtS,
                   asO, adO, asS, adS, HO, HS, SO, DO, SS, DS, N);
    }
}

// ---- layer-2 GEMM (branch pair via blockIdx.y, fp16 input) ----------------

__global__ __launch_bounds__(256) void k_gemm2(
    const __half* __restrict__ X0, const __half* __restrict__ X1,
    const _Float16* __restrict__ WtA, const _Float16* __restrict__ WtB,
    const float* __restrict__ as0, const float* __restrict__ ad0,
    const float* __restrict__ as1, const float* __restrict__ ad1,
    __half* __restrict__ H0, __half* __restrict__ H1,
    float* __restrict__ S0, float* __restrict__ D0,
    float* __restrict__ S1, float* __restrict__ D1,
    int n)
{
    int br = blockIdx.y;
    const __half* X = br ? X1 : X0;
    const _Float16* WtGp = br ? WtB : WtA;
    const float* a_src = br ? as1 : as0;
    const float* a_dst = br ? ad1 : ad0;
    __half* H = br ? H1 : H0;
    float* Svec = br ? S1 : S0;
    float* Dvec = br ? D1 : D0;

    __shared__ _Float16 As[64 * 136];
    __shared__ _Float16 Wt[128 * 136];
    int tid = threadIdx.x;
    int m0 = blockIdx.x * 64;

    for (int i = tid; i < WTSZ / 8; i += 256)
        ((uint4*)Wt)[i] = ((const uint4*)WtGp)[i];
    for (int i = tid; i < 64 * 16; i += 256) {
        int r = i >> 4;
        int c8 = (i & 15) << 3;
        int row = m0 + r; if (row >= n) row = n - 1;
        *(uint4*)&As[r * 136 + c8] = *(const uint4*)&X[(size_t)row * 128 + c8];
    }
    __syncthreads();

    int wave = tid >> 6;
    int lane = tid & 63;
    int m = lane & 15;
    int q = lane >> 4;
    int arow = wave * 16 + m;

    f32x4 acc[8];
    #pragma unroll
    for (int nt = 0; nt < 8; nt++) acc[nt] = (f32x4){0.f, 0.f, 0.f, 0.f};
    #pragma unroll
    for (int k0 = 0; k0 < 128; k0 += 32) {
        half8 a = *(half8*)&As[arow * 136 + k0 + q * 8];
        #pragma unroll
        for (int nt = 0; nt < 8; nt++) {
            half8 b = *(half8*)&Wt[(nt * 16 + m) * 136 + k0 + q * 8];
            acc[nt] = __builtin_amdgcn_mfma_f32_16x16x32_f16(a, b, acc[nt], 0, 0, 0);
        }
    }
    sd_epilogue(acc, a_src, a_dst, Svec, Dvec, m0, wave, lane, m, q, n);
    __syncthreads();
    d_to_lds(As, acc, wave, m, q);
    __syncthreads();
    lds_to_h(As, H, m0, tid, n);
}

// ---- aggregation core: one wave, one node (v1 — DO NOT TOUCH) -------------
// 16-edge groups, 4 gather loads in flight; w (float) and s (int) shuffled
// separately - short dependency chains. At the ~2.8-3.1 TB/s random-access
// service plateau (five structural variants all land here); needs max
// occupancy (VGPR<=48) to sustain — R8's prefetch regs cost 4%.

__device__ __forceinline__ void agg_core(
    const __half* __restrict__ H, const float* __restrict__ Svec, float dn,
    const unsigned short* __restrict__ idx, int beg, int end,
    int lane, int q, int subl, float* acc, float& denom)
{
    #pragma unroll
    for (int j = 0; j < 8; j++) acc[j] = 0.f;
    denom = 0.f;
    for (int base = beg; base < end; base += 64) {
        int cnt = min(64, end - base);
        float w = 0.f;
        int s = 0;
        if (lane < cnt) {
            s = idx[base + lane];
            w = __expf(LRELU(Svec[s] + dn));
        }
        denom += w;
        int cnt16 = (cnt + 15) & ~15;   // pad lanes carry w=0, s=0
        for (int kk = 0; kk < cnt16; kk += 16) {
            int k0 = kk + q;
            float w0 = __shfl(w, k0);
            float w1 = __shfl(w, k0 + 4);
            float w2 = __shfl(w, k0 + 8);
            float w3 = __shfl(w, k0 + 12);
            int s0 = __shfl(s, k0);
            int s1 = __shfl(s, k0 + 4);
            int s2 = __shfl(s, k0 + 8);
            int s3 = __shfl(s, k0 + 12);
            uint4 u0 = ((const uint4*)(H + (size_t)s0 * 128))[subl];
            uint4 u1 = ((const uint4*)(H + (size_t)s1 * 128))[subl];
            uint4 u2 = ((const uint4*)(H + (size_t)s2 * 128))[subl];
            uint4 u3 = ((const uint4*)(H + (size_t)s3 * 128))[subl];
            const _Float16* p;
            p = (const _Float16*)&u0;
            #pragma unroll
            for (int j = 0; j < 8; j++) acc[j] = fmaf((float)p[j], w0, acc[j]);
            p = (const _Float16*)&u1;
            #pragma unroll
            for (int j = 0; j < 8; j++) acc[j] = fmaf((float)p[j], w1, acc[j]);
            p = (const _Float16*)&u2;
            #pragma unroll
            for (int j = 0; j < 8; j++) acc[j] = fmaf((float)p[j], w2, acc[j]);
            p = (const _Float16*)&u3;
            #pragma unroll
            for (int j = 0; j < 8; j++) acc[j] = fmaf((float)p[j], w3, acc[j]);
        }
    }
    #pragma unroll
    for (int j = 0; j < 8; j++) {
        acc[j] += __shfl_xor(acc[j], 16);
        acc[j] += __shfl_xor(acc[j], 32);
    }
    #pragma unroll
    for (int o = 32; o; o >>= 1) denom += __shfl_xor(denom, o);
}

// ---- layer-1 aggregation (branch pair), fp16 out + relu -------------------

__global__ __launch_bounds__(256) void k_agg1(
    const __half* __restrict__ H0, const __half* __restrict__ H1,
    const float* __restrict__ S0, const float* __restrict__ D0,
    const float* __restrict__ S1, const float* __restrict__ D1,
    const int* __restrict__ off0, const int* __restrict__ dend0,
    const unsigned short* __restrict__ idx0,
    const int* __restrict__ off1, const int* __restrict__ dend1,
    const unsigned short* __restrict__ idx1,
    const float* __restrict__ b0, const float* __restrict__ b1,
    __half* __restrict__ out0, __half* __restrict__ out1,
    int n)
{
    int br = blockIdx.y;
    const __half* H = br ? H1 : H0;
    const float* Svec = br ? S1 : S0;
    const float* Dvec = br ? D1 : D0;
    const int* off  = br ? off1  : off0;
    const int* dend = br ? dend1 : dend0;
    const unsigned short* idx = br ? idx1 : idx0;
    const float* bias = br ? b1 : b0;
    __half* out = br ? out1 : out0;

    int wave = threadIdx.x >> 6;
    int lane = threadIdx.x & 63;
    int node = blockIdx.x * 4 + wave;
    if (node >= n) return;

    int q = lane >> 4;
    int subl = lane & 15;
    float acc[8], denom;
    agg_core(H, Svec, Dvec[node], idx, off[node], dend[node],
             lane, q, subl, acc, denom);

    if (q == 0) {
        float inv = 1.f / (denom + 1e-16f);
        int cb = subl << 3;
        half8 hv;
        #pragma unroll
        for (int j = 0; j < 8; j++) {
            float v = fmaxf(acc[j] * inv + bias[cb + j], 0.f);
            hv[j] = (_Float16)v;
        }
        *(half8*)&out[(size_t)node * 128 + cb] = hv;
    }
}

// ---- layer-2 aggregation + prediction head (both branches per wave) -------

__global__ __launch_bounds__(256) void k_agg_pred(
    const __half* __restrict__ H0, const __half* __restrict__ H1,
    const float* __restrict__ S0, const float* __restrict__ D0,
    const float* __restrict__ S1, const float* __restrict__ D1,
    const int* __restrict__ off0, const int* __restrict__ dend0,
    const unsigned short* __restrict__ idx0,
    const int* __restrict__ off1, const int* __restrict__ dend1,
    const unsigned short* __restrict__ idx1,
    const float* __restrict__ b0, const float* __restrict__ b1,
    const float* __restrict__ deg,
    const float* __restrict__ Wp, const float* __restrict__ bp,
    float* __restrict__ out, int n)
{
    int wave = threadIdx.x >> 6;
    int lane = threadIdx.x & 63;
    int node = blockIdx.x * 4 + wave;
    if (node >= n) return;

    int q = lane >> 4;
    int subl = lane & 15;
    int cb = subl << 3;

    float acc[8], denom;
    float vo[8], vs[8];

    agg_core(H0, S0, D0[node], idx0, off0[node], dend0[node],
             lane, q, subl, acc, denom);
    {
        float inv = 1.f / (denom + 1e-16f);
        #pragma unroll
        for (int j = 0; j < 8; j++) vo[j] = acc[j] * inv + b0[cb + j];
    }
    agg_core(H1, S1, D1[node], idx1, off1[node], dend1[node],
             lane, q, subl, acc, denom);
    {
        float inv = 1.f / (denom + 1e-16f);
        #pragma unroll
        for (int j = 0; j < 8; j++) vs[j] = acc[j] * inv + b1[cb + j];
    }

    if (q == 0) {
        float z0 = 0.f, z1 = 0.f;
        #pragma unroll
        for (int j = 0; j < 8; j++) {
            int c = cb + j;
            z0 = fmaf(vo[j], Wp[c * 2],     z0);
            z1 = fmaf(vo[j], Wp[c * 2 + 1], z1);
            z0 = fmaf(vs[j], Wp[(128 + c) * 2],     z0);
            z1 = fmaf(vs[j], Wp[(128 + c) * 2 + 1], z1);
        }
        float2 dv = *(const float2*)&deg[(size_t)node * 32 + 2 * subl];
        z0 = fmaf(dv.x, Wp[(256 + 2 * subl) * 2],     z0);
        z1 = fmaf(dv.x, Wp[(256 + 2 * subl) * 2 + 1], z1);
        z0 = fmaf(dv.y, Wp[(257 + 2 * subl) * 2],     z0);
        z1 = fmaf(dv.y, Wp[(257 + 2 * subl) * 2 + 1], z1);
        #pragma unroll
        for (int msk = 1; msk < 16; msk <<= 1) {
            z0 += __shfl_xor(z0, msk);
            z1 += __shfl_xor(z1, msk);
        }
        z0 += bp[0];
        z1 += bp[1];
        float mz = fmaxf(z0, z1);
        float e0 = __expf(z0 - mz);
        float e1 = __expf(z1 - mz);
        float a0 = e0 / (e0 + e1);
        float a1 = 1.f - a0;
        float4 r0, r1;
        r0.x = a0 * vo[0] + a1 * vs[0];
        r0.y = a0 * vo[1] + a1 * vs[1];
        r0.z = a0 * vo[2] + a1 * vs[2];
        r0.w = a0 * vo[3] + a1 * vs[3];
        r1.x = a0 * vo[4] + a1 * vs[4];
        r1.y = a0 * vo[5] + a1 * vs[5];
        r1.z = a0 * vo[6] + a1 * vs[6];
        r1.w = a0 * vo[7] + a1 * vs[7];
        *(float4*)&out[(size_t)node * 128 + cb] = r0;
        *(float4*)&out[(size_t)node * 128 + cb + 4] = r1;
    }
}

// ---- launch ----------------------------------------------------------------

extern "C" void kernel_launch(void* const* d_in, const int* in_sizes, int n_in,
                              void* d_out, int out_size, void* d_ws, size_t ws_size,
                              hipStream_t stream) {
    const float* x_o    = (const float*)d_in[0];
    const float* degree = (const float*)d_in[1];
    const int*   ei_o   = (const int*)d_in[2];
    const int*   ei_s   = (const int*)d_in[3];
    const float* W_o1 = (const float*)d_in[4];
    const float* asr_o1 = (const float*)d_in[5];
    const float* ads_o1 = (const float*)d_in[6];
    const float* b_o1 = (const float*)d_in[7];
    const float* W_o2 = (const float*)d_in[8];
    const float* asr_o2 = (const float*)d_in[9];
    const float* ads_o2 = (const float*)d_in[10];
    const float* b_o2 = (const float*)d_in[11];
    const float* W_s1 = (const float*)d_in[12];
    const float* asr_s1 = (const float*)d_in[13];
    const float* ads_s1 = (const float*)d_in[14];
    const float* b_s1 = (const float*)d_in[15];
    const float* W_s2 = (const float*)d_in[16];
    const float* asr_s2 = (const float*)d_in[17];
    const float* ads_s2 = (const float*)d_in[18];
    const float* b_s2 = (const float*)d_in[19];
    const float* W_pred = (const float*)d_in[20];
    const float* b_pred = (const float*)d_in[21];
    float* out = (float*)d_out;

    const int N = in_sizes[0] / 128;
    const int E = in_sizes[2] / 2;
    const int NBUCK = (N + BSIZE - 1) >> BSHIFT;

    char* ws = (char*)d_ws;
    size_t o = 0;
    auto alloc = [&](size_t bytes) -> char* {
        char* p = ws + o;
        o += (bytes + 255) & ~(size_t)255;
        return p;
    };
    int* bcur_o = (int*)alloc((size_t)NBUCK * 4);
    int* bcur_s = (int*)alloc((size_t)NBUCK * 4);
    int* off_o  = (int*)alloc((size_t)N * 4);
    int* dend_o = (int*)alloc((size_t)N * 4);
    int* off_s  = (int*)alloc((size_t)N * 4);
    int* dend_s = (int*)alloc((size_t)N * 4);
    unsigned short* idx_o = (unsigned short*)alloc((size_t)NBUCK * CAPI * 2);
    unsigned short* idx_s = (unsigned short*)alloc((size_t)NBUCK * CAPI * 2);
    _Float16* WtG = (_Float16*)alloc((size_t)4 * WTSZ * 2);
    float* Sv_o = (float*)alloc((size_t)N * 4);
    float* Dv_o = (float*)alloc((size_t)N * 4);
    float* Sv_s = (float*)alloc((size_t)N * 4);
    float* Dv_s = (float*)alloc((size_t)N * 4);
    __half* h_o   = (__half*)alloc((size_t)N * 128 * 2);
    __half* h_s   = (__half*)alloc((size_t)N * 128 * 2);
    __half* x1h_o = (__half*)alloc((size_t)N * 128 * 2);
    __half* x1h_s = (__half*)alloc((size_t)N * 128 * 2);
    (void)ws_size;

    // ebin regions overlay x1h (x1h first written by k_agg1, strictly after
    // the fused sort||gemm1 kernel; NBUCK*MAXE*4 = 6.8 MB <= N*128*2)
    int* ebin_o = (int*)x1h_o;
    int* ebin_s = (int*)x1h_s;

    dim3 blk(256);
    int gBin  = (E + CHUNK - 1) / CHUNK;
    int gGemm = (N + 63) / 64;
    int gNode = (N + 3) / 4;

    k_prepw<<<256, blk, 0, stream>>>(W_o1, W_o2, W_s1, W_s2, WtG,
                                     bcur_o, bcur_s, NBUCK);
    dim3 gB(gBin, 2);
    k_bin_scatter<<<gB, blk, 0, stream>>>(ei_o, ei_o + E, ei_s, ei_s + E,
                                          bcur_o, bcur_s, ebin_o, ebin_s, E);
    // fused: CSR sort (independent) || layer-1 GEMM
    k_sortgemm1<<<2 * NBUCK + gGemm, blk, 0, stream>>>(
        ebin_o, bcur_o, off_o, dend_o, idx_o,
        ebin_s, bcur_s, off_s, dend_s, idx_s,
        x_o, WtG, WtG + 2 * WTSZ,
        asr_o1, ads_o1, asr_s1, ads_s1,
        h_o, h_s, Sv_o, Dv_o, Sv_s, Dv_s, N, NBUCK);
    dim3 gA(gNode, 2);
    k_agg1<<<gA, blk, 0, stream>>>(
        h_o, h_s, Sv_o, Dv_o, Sv_s, Dv_s,
        off_o, dend_o, idx_o, off_s, dend_s, idx_s,
        b_o1, b_s1, x1h_o, x1h_s, N);
    // layer 2 (both branches) + fused prediction head
    dim3 gG(gGemm, 2);
    k_gemm2<<<gG, blk, 0, stream>>>(
        x1h_o, x1h_s, WtG + WTSZ, WtG + 3 * WTSZ,
        asr_o2, ads_o2, asr_s2, ads_s2,
        h_o, h_s, Sv_o, Dv_o, Sv_s, Dv_s, N);
    k_agg_pred<<<gNode, blk, 0, stream>>>(
        h_o, h_s, Sv_o, Dv_o, Sv_s, Dv_s,
        off_o, dend_o, idx_o, off_s, dend_s, idx_s,
        b_o2, b_s2, degree, W_pred, b_pred, out, N);
}